// Round 1
// baseline (22375.696 us; speedup 1.0000x reference)
//
#include <hip/hip_runtime.h>

#define V_NODES 50000
#define FDIM    512   // B*Cin
#define CIN     128
#define COUT    128
#define BATCH   4

// ---------------- transpose: x (B,Cin,V) -> x0 (V, B*Cin) -----------------
// Treated as plain 2D transpose of a (512, V) matrix.
__global__ __launch_bounds__(256) void transpose_kernel(const float* __restrict__ x,
                                                        float* __restrict__ x0) {
    __shared__ float tile[64][65];
    const int v0 = blockIdx.x * 64;
    const int r0 = blockIdx.y * 64;
    const int lane = threadIdx.x & 63;
    const int w = threadIdx.x >> 6;   // 0..3
    #pragma unroll
    for (int i = 0; i < 16; ++i) {
        int rr = w * 16 + i;
        int v = v0 + lane;
        tile[rr][lane] = (v < V_NODES) ? x[(size_t)(r0 + rr) * V_NODES + v] : 0.0f;
    }
    __syncthreads();
    #pragma unroll
    for (int i = 0; i < 16; ++i) {
        int vv = w * 16 + i;
        int v = v0 + vv;
        if (v < V_NODES) x0[(size_t)v * FDIM + r0 + lane] = tile[lane][vv];
    }
}

// ---------------- init: y = 0 (mode 0) or y = -y (mode 1) -----------------
__global__ __launch_bounds__(256) void init_kernel(float* __restrict__ y, int mode, int n4) {
    int t = blockIdx.x * blockDim.x + threadIdx.x;
    if (t >= n4) return;
    float4* y4 = (float4*)y;
    if (mode == 0) {
        y4[t] = make_float4(0.f, 0.f, 0.f, 0.f);
    } else {
        float4 v = y4[t];
        y4[t] = make_float4(-v.x, -v.y, -v.z, -v.w);
    }
}

// ---------------- SpMM (COO, atomic scatter): y[row] += alpha*val*x[col] ---
// 32 threads per edge, each thread handles 4 float4 (16 floats) of the 512.
__global__ __launch_bounds__(256) void spmm_kernel(const float* __restrict__ vals,
                                                   const int* __restrict__ rows,
                                                   const int* __restrict__ cols,
                                                   const float* __restrict__ xsrc,
                                                   float* __restrict__ y,
                                                   float alpha, int E) {
    long long t = (long long)blockIdx.x * blockDim.x + threadIdx.x;
    int e = (int)(t >> 5);
    int q = (int)(t & 31);
    if (e >= E) return;
    const float a = alpha * vals[e];
    const int col = cols[e];
    const int row = rows[e];
    const float4* xs = (const float4*)(xsrc + (size_t)col * FDIM);
    float* yd = y + (size_t)row * FDIM;
    #pragma unroll
    for (int i = 0; i < 4; ++i) {
        float4 xv = xs[q + 32 * i];
        float* p = yd + (size_t)(q + 32 * i) * 4;
        atomicAdd(p + 0, a * xv.x);
        atomicAdd(p + 1, a * xv.y);
        atomicAdd(p + 2, a * xv.z);
        atomicAdd(p + 3, a * xv.w);
    }
}

// ---------------- contraction: out(b,co,v) (+)= sum_ci xk(v,b,ci)*W(ci,co) --
// Block: 64 v-lanes x 4 waves; each wave owns 32 co's; acc[32] per thread.
__global__ __launch_bounds__(256) void gemm_kernel(const float* __restrict__ xk,
                                                   const float* __restrict__ W,
                                                   const float* __restrict__ bias,
                                                   float* __restrict__ out, int kinit) {
    __shared__ float xl[64][33];     // padded: stride 33 -> conflict-free
    __shared__ float wl[32][128];
    const int lane = threadIdx.x & 63;
    const int wv = threadIdx.x >> 6;     // 0..3
    const int v0 = blockIdx.x * 64;
    const int b = blockIdx.y;
    const int v = v0 + lane;

    float acc[32];
    #pragma unroll
    for (int j = 0; j < 32; ++j) acc[j] = 0.f;

    for (int cc = 0; cc < CIN; cc += 32) {
        for (int e = threadIdx.x; e < 64 * 32; e += 256) {
            int vv = e >> 5, ci = e & 31;
            int gv = v0 + vv;
            xl[vv][ci] = (gv < V_NODES) ? xk[(size_t)gv * FDIM + b * CIN + cc + ci] : 0.f;
        }
        for (int e = threadIdx.x; e < 32 * 128; e += 256) {
            int ci = e >> 7, co = e & 127;
            wl[ci][co] = W[(cc + ci) * COUT + co];
        }
        __syncthreads();
        #pragma unroll
        for (int ci = 0; ci < 32; ++ci) {
            float xr = xl[lane][ci];
            const float4* wr = (const float4*)&wl[ci][wv * 32];
            #pragma unroll
            for (int j4 = 0; j4 < 8; ++j4) {
                float4 w4 = wr[j4];
                acc[j4 * 4 + 0] += xr * w4.x;
                acc[j4 * 4 + 1] += xr * w4.y;
                acc[j4 * 4 + 2] += xr * w4.z;
                acc[j4 * 4 + 3] += xr * w4.w;
            }
        }
        __syncthreads();
    }

    if (v < V_NODES) {
        #pragma unroll
        for (int j = 0; j < 32; ++j) {
            int co = wv * 32 + j;
            size_t idx = (size_t)(b * COUT + co) * V_NODES + v;
            if (kinit) out[idx] = acc[j] + bias[co];
            else       out[idx] += acc[j];
        }
    }
}

extern "C" void kernel_launch(void* const* d_in, const int* in_sizes, int n_in,
                              void* d_out, int out_size, void* d_ws, size_t ws_size,
                              hipStream_t stream) {
    const float* x    = (const float*)d_in[0];
    const float* vals = (const float*)d_in[1];
    const float* W    = (const float*)d_in[2];
    const float* bias = (const float*)d_in[3];
    const int* rows   = (const int*)d_in[4];
    const int* cols   = (const int*)d_in[5];
    const int E = in_sizes[1];
    float* out = (float*)d_out;

    float* A  = (float*)d_ws;                       // (V,512)
    float* Bf = A + (size_t)V_NODES * FDIM;         // (V,512)

    const int vblk = (V_NODES + 63) / 64;           // 782
    dim3 tg(vblk, FDIM / 64);                       // transpose grid
    dim3 gg(vblk, BATCH);                           // gemm grid
    const int n4 = V_NODES * FDIM / 4;
    const int initBlocks = (n4 + 255) / 256;
    const long long spThreads = (long long)E * 32;
    const int spBlocks = (int)((spThreads + 255) / 256);

    // T0 = A
    transpose_kernel<<<tg, 256, 0, stream>>>(x, A);
    gemm_kernel<<<gg, 256, 0, stream>>>(A, W + 0 * CIN * COUT, bias, out, 1);

    // T1 = B = L*A
    init_kernel<<<initBlocks, 256, 0, stream>>>(Bf, 0, n4);
    spmm_kernel<<<spBlocks, 256, 0, stream>>>(vals, rows, cols, A, Bf, 1.f, E);
    gemm_kernel<<<gg, 256, 0, stream>>>(Bf, W + 1 * CIN * COUT, bias, out, 0);

    // T2: A = 2*L*B - A   (in place: A = -A; A += 2*L*B)
    init_kernel<<<initBlocks, 256, 0, stream>>>(A, 1, n4);
    spmm_kernel<<<spBlocks, 256, 0, stream>>>(vals, rows, cols, Bf, A, 2.f, E);
    gemm_kernel<<<gg, 256, 0, stream>>>(A, W + 2 * CIN * COUT, bias, out, 0);

    // T3: B = 2*L*A - B
    init_kernel<<<initBlocks, 256, 0, stream>>>(Bf, 1, n4);
    spmm_kernel<<<spBlocks, 256, 0, stream>>>(vals, rows, cols, A, Bf, 2.f, E);
    gemm_kernel<<<gg, 256, 0, stream>>>(Bf, W + 3 * CIN * COUT, bias, out, 0);

    // T4: A = 2*L*B - A
    init_kernel<<<initBlocks, 256, 0, stream>>>(A, 1, n4);
    spmm_kernel<<<spBlocks, 256, 0, stream>>>(vals, rows, cols, Bf, A, 2.f, E);
    gemm_kernel<<<gg, 256, 0, stream>>>(A, W + 4 * CIN * COUT, bias, out, 0);
}

// Round 2
// 2299.596 us; speedup vs baseline: 9.7303x; 9.7303x over previous
//
#include <hip/hip_runtime.h>

#define V_NODES 50000
#define FDIM    512   // B*Cin
#define F4      128   // FDIM/4
#define CIN     128
#define COUT    128
#define BATCH   4

// ---------------- transpose: x (B,Cin,V) -> x0 (V, B*Cin) -----------------
__global__ __launch_bounds__(256) void transpose_kernel(const float* __restrict__ x,
                                                        float* __restrict__ x0) {
    __shared__ float tile[64][65];
    const int v0 = blockIdx.x * 64;
    const int r0 = blockIdx.y * 64;
    const int lane = threadIdx.x & 63;
    const int w = threadIdx.x >> 6;   // 0..3
    #pragma unroll
    for (int i = 0; i < 16; ++i) {
        int rr = w * 16 + i;
        int v = v0 + lane;
        tile[rr][lane] = (v < V_NODES) ? x[(size_t)(r0 + rr) * V_NODES + v] : 0.0f;
    }
    __syncthreads();
    #pragma unroll
    for (int i = 0; i < 16; ++i) {
        int vv = w * 16 + i;
        int v = v0 + vv;
        if (v < V_NODES) x0[(size_t)v * FDIM + r0 + lane] = tile[lane][vv];
    }
}

// ---------------- CSR build ------------------------------------------------
__global__ __launch_bounds__(256) void zero_cnt_kernel(int* __restrict__ cnt) {
    int t = blockIdx.x * 256 + threadIdx.x;
    if (t < V_NODES) cnt[t] = 0;
}

__global__ __launch_bounds__(256) void hist_kernel(const int* __restrict__ rows,
                                                   int* __restrict__ cnt, int E) {
    int e = blockIdx.x * 256 + threadIdx.x;
    if (e < E) atomicAdd(&cnt[rows[e]], 1);
}

// single-block exclusive scan over V_NODES counts -> rowPtr[V+1], cursor[V]
__global__ __launch_bounds__(1024) void scan_kernel(const int* __restrict__ cnt,
                                                    int* __restrict__ rowPtr,
                                                    int* __restrict__ cursor) {
    __shared__ int partial[1024];
    const int T = 1024;
    const int chunk = (V_NODES + T - 1) / T;   // 49
    const int t = threadIdx.x;
    int lo = t * chunk, hi = min(lo + chunk, V_NODES);
    int s = 0;
    for (int i = lo; i < hi; ++i) s += cnt[i];
    partial[t] = s;
    __syncthreads();
    for (int off = 1; off < T; off <<= 1) {
        int v = (t >= off) ? partial[t - off] : 0;
        __syncthreads();
        partial[t] += v;
        __syncthreads();
    }
    int base = (t == 0) ? 0 : partial[t - 1];
    for (int i = lo; i < hi; ++i) {
        rowPtr[i] = base;
        cursor[i] = base;
        base += cnt[i];
    }
    if (t == T - 1) rowPtr[V_NODES] = base;
}

__global__ __launch_bounds__(256) void scatter_kernel(const float* __restrict__ vals,
                                                      const int* __restrict__ rows,
                                                      const int* __restrict__ cols,
                                                      int* __restrict__ cursor,
                                                      float* __restrict__ svals,
                                                      int* __restrict__ scols, int E) {
    int e = blockIdx.x * 256 + threadIdx.x;
    if (e >= E) return;
    int r = rows[e];
    int pos = atomicAdd(&cursor[r], 1);
    svals[pos] = vals[e];
    scols[pos] = cols[e];
}

// ---------------- CSR SpMM: y[row] = alpha * sum(val*x[col]) - beta*old[row]
// one block (128 thr) per row; thread t owns float4 #t of the 512 features.
__global__ __launch_bounds__(128) void spmm_csr_kernel(const float* __restrict__ svals,
                                                       const int* __restrict__ scols,
                                                       const int* __restrict__ rowPtr,
                                                       const float* __restrict__ xsrc,
                                                       const float* __restrict__ xold,
                                                       float* __restrict__ y,
                                                       float alpha, int beta) {
    const int row = blockIdx.x;
    const int t = threadIdx.x;
    const int s = rowPtr[row], e_end = rowPtr[row + 1];
    const float4* __restrict__ xs4 = (const float4*)xsrc;

    float4 acc0 = make_float4(0.f, 0.f, 0.f, 0.f);
    float4 acc1 = make_float4(0.f, 0.f, 0.f, 0.f);
    int e = s;
    for (; e + 1 < e_end; e += 2) {
        float a0 = svals[e],     a1 = svals[e + 1];
        int   c0 = scols[e],     c1 = scols[e + 1];
        float4 v0 = xs4[(size_t)c0 * F4 + t];
        float4 v1 = xs4[(size_t)c1 * F4 + t];
        acc0.x += a0 * v0.x; acc0.y += a0 * v0.y; acc0.z += a0 * v0.z; acc0.w += a0 * v0.w;
        acc1.x += a1 * v1.x; acc1.y += a1 * v1.y; acc1.z += a1 * v1.z; acc1.w += a1 * v1.w;
    }
    if (e < e_end) {
        float a0 = svals[e];
        int   c0 = scols[e];
        float4 v0 = xs4[(size_t)c0 * F4 + t];
        acc0.x += a0 * v0.x; acc0.y += a0 * v0.y; acc0.z += a0 * v0.z; acc0.w += a0 * v0.w;
    }
    float4 r;
    r.x = alpha * (acc0.x + acc1.x);
    r.y = alpha * (acc0.y + acc1.y);
    r.z = alpha * (acc0.z + acc1.z);
    r.w = alpha * (acc0.w + acc1.w);
    if (beta) {
        float4 o = ((const float4*)xold)[(size_t)row * F4 + t];
        r.x -= o.x; r.y -= o.y; r.z -= o.z; r.w -= o.w;
    }
    ((float4*)y)[(size_t)row * F4 + t] = r;
}

// ---------------- contraction: out(b,co,v) (+)= sum_ci xk(v,b,ci)*W(ci,co) --
__global__ __launch_bounds__(256) void gemm_kernel(const float* __restrict__ xk,
                                                   const float* __restrict__ W,
                                                   const float* __restrict__ bias,
                                                   float* __restrict__ out, int kinit) {
    __shared__ float xl[64][33];
    __shared__ float wl[32][128];
    const int lane = threadIdx.x & 63;
    const int wv = threadIdx.x >> 6;
    const int v0 = blockIdx.x * 64;
    const int b = blockIdx.y;
    const int v = v0 + lane;

    float acc[32];
    #pragma unroll
    for (int j = 0; j < 32; ++j) acc[j] = 0.f;

    for (int cc = 0; cc < CIN; cc += 32) {
        for (int e = threadIdx.x; e < 64 * 32; e += 256) {
            int vv = e >> 5, ci = e & 31;
            int gv = v0 + vv;
            xl[vv][ci] = (gv < V_NODES) ? xk[(size_t)gv * FDIM + b * CIN + cc + ci] : 0.f;
        }
        for (int e = threadIdx.x; e < 32 * 128; e += 256) {
            int ci = e >> 7, co = e & 127;
            wl[ci][co] = W[(cc + ci) * COUT + co];
        }
        __syncthreads();
        #pragma unroll
        for (int ci = 0; ci < 32; ++ci) {
            float xr = xl[lane][ci];
            const float4* wr = (const float4*)&wl[ci][wv * 32];
            #pragma unroll
            for (int j4 = 0; j4 < 8; ++j4) {
                float4 w4 = wr[j4];
                acc[j4 * 4 + 0] += xr * w4.x;
                acc[j4 * 4 + 1] += xr * w4.y;
                acc[j4 * 4 + 2] += xr * w4.z;
                acc[j4 * 4 + 3] += xr * w4.w;
            }
        }
        __syncthreads();
    }

    if (v < V_NODES) {
        #pragma unroll
        for (int j = 0; j < 32; ++j) {
            int co = wv * 32 + j;
            size_t idx = (size_t)(b * COUT + co) * V_NODES + v;
            if (kinit) out[idx] = acc[j] + bias[co];
            else       out[idx] += acc[j];
        }
    }
}

extern "C" void kernel_launch(void* const* d_in, const int* in_sizes, int n_in,
                              void* d_out, int out_size, void* d_ws, size_t ws_size,
                              hipStream_t stream) {
    const float* x    = (const float*)d_in[0];
    const float* vals = (const float*)d_in[1];
    const float* W    = (const float*)d_in[2];
    const float* bias = (const float*)d_in[3];
    const int* rows   = (const int*)d_in[4];
    const int* cols   = (const int*)d_in[5];
    const int E = in_sizes[1];
    float* out = (float*)d_out;

    // workspace layout
    float* A     = (float*)d_ws;                          // (V,512) f32
    float* Bf    = A + (size_t)V_NODES * FDIM;            // (V,512) f32
    float* svals = Bf + (size_t)V_NODES * FDIM;           // E f32
    int*   scols = (int*)(svals + E);                     // E i32
    int*   rowPtr= scols + E;                             // V+1
    int*   cursor= rowPtr + V_NODES + 1;                  // V
    int*   cnt   = cursor + V_NODES;                      // V

    const int vblk = (V_NODES + 63) / 64;                 // 782
    dim3 tg(vblk, FDIM / 64);
    dim3 gg(vblk, BATCH);
    const int eBlocks = (E + 255) / 256;
    const int vBlocks = (V_NODES + 255) / 256;

    // --- CSR build ---
    zero_cnt_kernel<<<vBlocks, 256, 0, stream>>>(cnt);
    hist_kernel<<<eBlocks, 256, 0, stream>>>(rows, cnt, E);
    scan_kernel<<<1, 1024, 0, stream>>>(cnt, rowPtr, cursor);
    scatter_kernel<<<eBlocks, 256, 0, stream>>>(vals, rows, cols, cursor, svals, scols, E);

    // --- T0 ---
    transpose_kernel<<<tg, 256, 0, stream>>>(x, A);
    gemm_kernel<<<gg, 256, 0, stream>>>(A, W + 0 * CIN * COUT, bias, out, 1);

    // --- T1 = L*x0 ---
    spmm_csr_kernel<<<V_NODES, 128, 0, stream>>>(svals, scols, rowPtr, A, A, Bf, 1.f, 0);
    gemm_kernel<<<gg, 256, 0, stream>>>(Bf, W + 1 * CIN * COUT, bias, out, 0);

    // --- T2 = 2*L*T1 - T0  (reads B gather, old A, writes A) ---
    spmm_csr_kernel<<<V_NODES, 128, 0, stream>>>(svals, scols, rowPtr, Bf, A, A, 2.f, 1);
    gemm_kernel<<<gg, 256, 0, stream>>>(A, W + 2 * CIN * COUT, bias, out, 0);

    // --- T3 = 2*L*T2 - T1 ---
    spmm_csr_kernel<<<V_NODES, 128, 0, stream>>>(svals, scols, rowPtr, A, Bf, Bf, 2.f, 1);
    gemm_kernel<<<gg, 256, 0, stream>>>(Bf, W + 3 * CIN * COUT, bias, out, 0);

    // --- T4 = 2*L*T3 - T2 ---
    spmm_csr_kernel<<<V_NODES, 128, 0, stream>>>(svals, scols, rowPtr, Bf, A, A, 2.f, 1);
    gemm_kernel<<<gg, 256, 0, stream>>>(A, W + 4 * CIN * COUT, bias, out, 0);
}

// Round 3
// 944.130 us; speedup vs baseline: 23.6998x; 2.4357x over previous
//
#include <hip/hip_runtime.h>

#define V_NODES 50000
#define FDIM    512   // B*Cin
#define CIN     128
#define COUT    128
#define BATCH   4
#define KORD    5
#define KTOT    (KORD * CIN)   // 640

typedef short s16x8 __attribute__((ext_vector_type(8)));
typedef float f32x4 __attribute__((ext_vector_type(4)));

__device__ __forceinline__ float bf2f(unsigned short u) {
    union { unsigned int i; float f; } x; x.i = ((unsigned int)u) << 16; return x.f;
}
__device__ __forceinline__ unsigned short f2bf(float f) {
    union { float f; unsigned int i; } x; x.f = f;
    unsigned int r = x.i + 0x7fffu + ((x.i >> 16) & 1u);   // RNE
    return (unsigned short)(r >> 16);
}

// ---------------- transpose: x (512, V) f32 -> T0 (V, 512) bf16 ------------
__global__ __launch_bounds__(256) void transpose_kernel(const float* __restrict__ x,
                                                        unsigned short* __restrict__ t0) {
    __shared__ float tile[64][65];
    const int v0 = blockIdx.x * 64;
    const int r0 = blockIdx.y * 64;
    const int lane = threadIdx.x & 63;
    const int w = threadIdx.x >> 6;
    #pragma unroll
    for (int i = 0; i < 16; ++i) {
        int rr = w * 16 + i;
        int v = v0 + lane;
        tile[rr][lane] = (v < V_NODES) ? x[(size_t)(r0 + rr) * V_NODES + v] : 0.0f;
    }
    __syncthreads();
    #pragma unroll
    for (int i = 0; i < 16; ++i) {
        int vv = w * 16 + i;
        int v = v0 + vv;
        if (v < V_NODES) t0[(size_t)v * FDIM + r0 + lane] = f2bf(tile[lane][vv]);
    }
}

// ---------------- W convert+transpose: W f32 [kci][co] -> WbT bf16 [co][kci]
__global__ __launch_bounds__(256) void convw_kernel(const float* __restrict__ W,
                                                    unsigned short* __restrict__ WbT) {
    int t = blockIdx.x * 256 + threadIdx.x;
    if (t >= KTOT * COUT) return;
    int kci = t >> 7, co = t & 127;
    WbT[(size_t)co * KTOT + kci] = f2bf(W[(size_t)kci * COUT + co]);
}

// ---------------- CSR build ------------------------------------------------
__global__ __launch_bounds__(256) void zero_cnt_kernel(int* __restrict__ cnt) {
    int t = blockIdx.x * 256 + threadIdx.x;
    if (t < V_NODES) cnt[t] = 0;
}

__global__ __launch_bounds__(256) void hist_kernel(const int* __restrict__ rows,
                                                   int* __restrict__ cnt, int E) {
    int e = blockIdx.x * 256 + threadIdx.x;
    if (e < E) atomicAdd(&cnt[rows[e]], 1);
}

__global__ __launch_bounds__(1024) void scan_kernel(const int* __restrict__ cnt,
                                                    int* __restrict__ rowPtr,
                                                    int* __restrict__ cursor) {
    __shared__ int partial[1024];
    const int T = 1024;
    const int chunk = (V_NODES + T - 1) / T;
    const int t = threadIdx.x;
    int lo = t * chunk, hi = min(lo + chunk, V_NODES);
    int s = 0;
    for (int i = lo; i < hi; ++i) s += cnt[i];
    partial[t] = s;
    __syncthreads();
    for (int off = 1; off < T; off <<= 1) {
        int v = (t >= off) ? partial[t - off] : 0;
        __syncthreads();
        partial[t] += v;
        __syncthreads();
    }
    int base = (t == 0) ? 0 : partial[t - 1];
    for (int i = lo; i < hi; ++i) {
        rowPtr[i] = base;
        cursor[i] = base;
        base += cnt[i];
    }
    if (t == T - 1) rowPtr[V_NODES] = base;
}

__global__ __launch_bounds__(256) void scatter_kernel(const float* __restrict__ vals,
                                                      const int* __restrict__ rows,
                                                      const int* __restrict__ cols,
                                                      int* __restrict__ cursor,
                                                      float* __restrict__ svals,
                                                      int* __restrict__ scols, int E) {
    int e = blockIdx.x * 256 + threadIdx.x;
    if (e >= E) return;
    int r = rows[e];
    int pos = atomicAdd(&cursor[r], 1);
    svals[pos] = vals[e];
    scols[pos] = cols[e];
}

// ---------------- CSR SpMM bf16: y[row] = a*sum(val*x[col]) - beta*old[row]
// one wave per row; lane owns 8 bf16 (one uint4) of the 512-wide feature row.
__global__ __launch_bounds__(256) void spmm_bf16_kernel(const float* __restrict__ svals,
                                                        const int* __restrict__ scols,
                                                        const int* __restrict__ rowPtr,
                                                        const unsigned short* __restrict__ xsrc,
                                                        const unsigned short* __restrict__ xold,
                                                        unsigned short* __restrict__ y,
                                                        float alpha, int beta) {
    const int wid = threadIdx.x >> 6;
    const int lane = threadIdx.x & 63;
    const int row = blockIdx.x * 4 + wid;
    if (row >= V_NODES) return;
    const int s = rowPtr[row], e_end = rowPtr[row + 1];
    const uint4* __restrict__ xs = (const uint4*)xsrc;   // 64 uint4 per row

    float a0[8], a1[8];
    #pragma unroll
    for (int j = 0; j < 8; ++j) { a0[j] = 0.f; a1[j] = 0.f; }

    int e = s;
    for (; e + 1 < e_end; e += 2) {
        float w0 = svals[e], w1 = svals[e + 1];
        int c0 = scols[e], c1 = scols[e + 1];
        uint4 q0 = xs[(size_t)c0 * 64 + lane];
        uint4 q1 = xs[(size_t)c1 * 64 + lane];
        unsigned int u0[4] = {q0.x, q0.y, q0.z, q0.w};
        unsigned int u1[4] = {q1.x, q1.y, q1.z, q1.w};
        #pragma unroll
        for (int j = 0; j < 4; ++j) {
            a0[2*j+0] += w0 * bf2f((unsigned short)(u0[j] & 0xffffu));
            a0[2*j+1] += w0 * bf2f((unsigned short)(u0[j] >> 16));
            a1[2*j+0] += w1 * bf2f((unsigned short)(u1[j] & 0xffffu));
            a1[2*j+1] += w1 * bf2f((unsigned short)(u1[j] >> 16));
        }
    }
    if (e < e_end) {
        float w0 = svals[e];
        int c0 = scols[e];
        uint4 q0 = xs[(size_t)c0 * 64 + lane];
        unsigned int u0[4] = {q0.x, q0.y, q0.z, q0.w};
        #pragma unroll
        for (int j = 0; j < 4; ++j) {
            a0[2*j+0] += w0 * bf2f((unsigned short)(u0[j] & 0xffffu));
            a0[2*j+1] += w0 * bf2f((unsigned short)(u0[j] >> 16));
        }
    }

    float r[8];
    #pragma unroll
    for (int j = 0; j < 8; ++j) r[j] = alpha * (a0[j] + a1[j]);
    if (beta) {
        uint4 q = ((const uint4*)xold)[(size_t)row * 64 + lane];
        unsigned int u[4] = {q.x, q.y, q.z, q.w};
        #pragma unroll
        for (int j = 0; j < 4; ++j) {
            r[2*j+0] -= bf2f((unsigned short)(u[j] & 0xffffu));
            r[2*j+1] -= bf2f((unsigned short)(u[j] >> 16));
        }
    }
    uint4 o;
    unsigned int* ou = (unsigned int*)&o;
    #pragma unroll
    for (int j = 0; j < 4; ++j)
        ou[j] = (unsigned int)f2bf(r[2*j]) | ((unsigned int)f2bf(r[2*j+1]) << 16);
    ((uint4*)y)[(size_t)row * 64 + lane] = o;
}

// ---------------- fused MFMA GEMM over all K orders ------------------------
// out[b,co,v] = sum_{kci<640} T[kci>>7][v, b*128 + (kci&127)] * WbT[co][kci] + bias[co]
// block: 256 thr = 4 waves; tile 128 v x 128 co; wave wv owns co in [wv*32, wv*32+32)
__global__ __launch_bounds__(256) void gemm_mfma_kernel(const unsigned short* __restrict__ T,
                                                        const unsigned short* __restrict__ WbT,
                                                        const float* __restrict__ bias,
                                                        float* __restrict__ out) {
    const int lane = threadIdx.x & 63;
    const int wv = threadIdx.x >> 6;
    const int v0 = blockIdx.x * 128;
    const int b = blockIdx.y;
    const int lr = lane & 15;   // A-row / B-col / D-col within fragment
    const int lk = lane >> 4;   // k-group (8 elems each)

    f32x4 acc[8][2];
    #pragma unroll
    for (int mf = 0; mf < 8; ++mf)
        #pragma unroll
        for (int nf = 0; nf < 2; ++nf)
            acc[mf][nf] = (f32x4){0.f, 0.f, 0.f, 0.f};

    #pragma unroll 1
    for (int step = 0; step < KTOT / 32; ++step) {   // 20 steps
        const int kk0 = step * 32;
        const int korder = kk0 >> 7;
        const int ci0 = kk0 & 127;
        const unsigned short* Tb = T + (size_t)korder * V_NODES * FDIM + b * CIN + ci0 + lk * 8;

        s16x8 a[8], bf[2];
        #pragma unroll
        for (int mf = 0; mf < 8; ++mf) {
            int v = v0 + mf * 16 + lr;
            if (v >= V_NODES) v = V_NODES - 1;        // clamp; masked at write
            a[mf] = *(const s16x8*)(Tb + (size_t)v * FDIM);
        }
        #pragma unroll
        for (int nf = 0; nf < 2; ++nf) {
            int co = wv * 32 + nf * 16 + lr;
            bf[nf] = *(const s16x8*)(WbT + (size_t)co * KTOT + kk0 + lk * 8);
        }
        #pragma unroll
        for (int mf = 0; mf < 8; ++mf)
            #pragma unroll
            for (int nf = 0; nf < 2; ++nf)
                acc[mf][nf] = __builtin_amdgcn_mfma_f32_16x16x32_bf16(a[mf], bf[nf], acc[mf][nf], 0, 0, 0);
    }

    #pragma unroll
    for (int nf = 0; nf < 2; ++nf) {
        int co = wv * 32 + nf * 16 + lr;
        float bs = bias[co];
        float* ob = out + (size_t)(b * COUT + co) * V_NODES;
        #pragma unroll
        for (int mf = 0; mf < 8; ++mf) {
            #pragma unroll
            for (int r = 0; r < 4; ++r) {
                int v = v0 + mf * 16 + lk * 4 + r;
                if (v < V_NODES) ob[v] = acc[mf][nf][r] + bs;
            }
        }
    }
}

extern "C" void kernel_launch(void* const* d_in, const int* in_sizes, int n_in,
                              void* d_out, int out_size, void* d_ws, size_t ws_size,
                              hipStream_t stream) {
    const float* x    = (const float*)d_in[0];
    const float* vals = (const float*)d_in[1];
    const float* W    = (const float*)d_in[2];
    const float* bias = (const float*)d_in[3];
    const int* rows   = (const int*)d_in[4];
    const int* cols   = (const int*)d_in[5];
    const int E = in_sizes[1];
    float* out = (float*)d_out;

    // workspace: T0..T4 bf16 (each V*512), WbT bf16, CSR arrays
    unsigned short* T    = (unsigned short*)d_ws;
    unsigned short* WbT  = T + (size_t)KORD * V_NODES * FDIM;
    float* svals  = (float*)(WbT + (size_t)COUT * KTOT);
    int*   scols  = (int*)(svals + E);
    int*   rowPtr = scols + E;
    int*   cursor = rowPtr + V_NODES + 1;
    int*   cnt    = cursor + V_NODES;

    unsigned short* T0 = T;
    unsigned short* T1 = T + 1 * (size_t)V_NODES * FDIM;
    unsigned short* T2 = T + 2 * (size_t)V_NODES * FDIM;
    unsigned short* T3 = T + 3 * (size_t)V_NODES * FDIM;
    unsigned short* T4 = T + 4 * (size_t)V_NODES * FDIM;

    const int eBlocks = (E + 255) / 256;
    const int vBlocks = (V_NODES + 255) / 256;
    const int spBlocks = (V_NODES + 3) / 4;

    // CSR build
    zero_cnt_kernel<<<vBlocks, 256, 0, stream>>>(cnt);
    hist_kernel<<<eBlocks, 256, 0, stream>>>(rows, cnt, E);
    scan_kernel<<<1, 1024, 0, stream>>>(cnt, rowPtr, cursor);
    scatter_kernel<<<eBlocks, 256, 0, stream>>>(vals, rows, cols, cursor, svals, scols, E);

    // T0 + weights
    dim3 tg((V_NODES + 63) / 64, FDIM / 64);
    transpose_kernel<<<tg, 256, 0, stream>>>(x, T0);
    convw_kernel<<<(KTOT * COUT + 255) / 256, 256, 0, stream>>>(W, WbT);

    // Chebyshev recurrence (all bf16)
    spmm_bf16_kernel<<<spBlocks, 256, 0, stream>>>(svals, scols, rowPtr, T0, T0, T1, 1.f, 0);
    spmm_bf16_kernel<<<spBlocks, 256, 0, stream>>>(svals, scols, rowPtr, T1, T0, T2, 2.f, 1);
    spmm_bf16_kernel<<<spBlocks, 256, 0, stream>>>(svals, scols, rowPtr, T2, T1, T3, 2.f, 1);
    spmm_bf16_kernel<<<spBlocks, 256, 0, stream>>>(svals, scols, rowPtr, T3, T2, T4, 2.f, 1);

    // fused contraction over all 5 orders
    dim3 gg((V_NODES + 127) / 128, BATCH);
    gemm_mfma_kernel<<<gg, 256, 0, stream>>>(T, WbT, bias, out);
}

// Round 4
// 806.117 us; speedup vs baseline: 27.7574x; 1.1712x over previous
//
#include <hip/hip_runtime.h>

#define V_NODES 50000
#define FDIM    512   // B*Cin
#define CIN     128
#define COUT    128
#define BATCH   4
#define KORD    5
#define KTOT    (KORD * CIN)   // 640

typedef short s16x8 __attribute__((ext_vector_type(8)));
typedef float f32x4 __attribute__((ext_vector_type(4)));

__device__ __forceinline__ float bf2f(unsigned short u) {
    union { unsigned int i; float f; } x; x.i = ((unsigned int)u) << 16; return x.f;
}
__device__ __forceinline__ unsigned short f2bf(float f) {
    union { float f; unsigned int i; } x; x.f = f;
    unsigned int r = x.i + 0x7fffu + ((x.i >> 16) & 1u);   // RNE
    return (unsigned short)(r >> 16);
}

// ---------------- transpose: x (512, V) f32 -> T0 (V, 512) bf16 ------------
__global__ __launch_bounds__(256) void transpose_kernel(const float* __restrict__ x,
                                                        unsigned short* __restrict__ t0) {
    __shared__ float tile[64][65];
    const int v0 = blockIdx.x * 64;
    const int r0 = blockIdx.y * 64;
    const int lane = threadIdx.x & 63;
    const int w = threadIdx.x >> 6;
    #pragma unroll
    for (int i = 0; i < 16; ++i) {
        int rr = w * 16 + i;
        int v = v0 + lane;
        tile[rr][lane] = (v < V_NODES) ? x[(size_t)(r0 + rr) * V_NODES + v] : 0.0f;
    }
    __syncthreads();
    #pragma unroll
    for (int i = 0; i < 16; ++i) {
        int vv = w * 16 + i;
        int v = v0 + vv;
        if (v < V_NODES) t0[(size_t)v * FDIM + r0 + lane] = f2bf(tile[lane][vv]);
    }
}

// ---------------- W convert+transpose: W f32 [kci][co] -> WbT bf16 [co][kci]
__global__ __launch_bounds__(256) void convw_kernel(const float* __restrict__ W,
                                                    unsigned short* __restrict__ WbT) {
    int t = blockIdx.x * 256 + threadIdx.x;
    if (t >= KTOT * COUT) return;
    int kci = t >> 7, co = t & 127;
    WbT[(size_t)co * KTOT + kci] = f2bf(W[(size_t)kci * COUT + co]);
}

// ---------------- CSR build ------------------------------------------------
__global__ __launch_bounds__(256) void zero_cnt_kernel(int* __restrict__ cnt) {
    int t = blockIdx.x * 256 + threadIdx.x;
    if (t < V_NODES) cnt[t] = 0;
}

__global__ __launch_bounds__(256) void hist_kernel(const int* __restrict__ rows,
                                                   int* __restrict__ cnt, int E) {
    int e = blockIdx.x * 256 + threadIdx.x;
    if (e < E) atomicAdd(&cnt[rows[e]], 1);
}

__global__ __launch_bounds__(1024) void scan_kernel(const int* __restrict__ cnt,
                                                    int* __restrict__ rowPtr,
                                                    int* __restrict__ cursor) {
    __shared__ int partial[1024];
    const int T = 1024;
    const int chunk = (V_NODES + T - 1) / T;
    const int t = threadIdx.x;
    int lo = t * chunk, hi = min(lo + chunk, V_NODES);
    int s = 0;
    for (int i = lo; i < hi; ++i) s += cnt[i];
    partial[t] = s;
    __syncthreads();
    for (int off = 1; off < T; off <<= 1) {
        int v = (t >= off) ? partial[t - off] : 0;
        __syncthreads();
        partial[t] += v;
        __syncthreads();
    }
    int base = (t == 0) ? 0 : partial[t - 1];
    for (int i = lo; i < hi; ++i) {
        rowPtr[i] = base;
        cursor[i] = base;
        base += cnt[i];
    }
    if (t == T - 1) rowPtr[V_NODES] = base;
}

__global__ __launch_bounds__(256) void scatter_kernel(const float* __restrict__ vals,
                                                      const int* __restrict__ rows,
                                                      const int* __restrict__ cols,
                                                      int* __restrict__ cursor,
                                                      float* __restrict__ svals,
                                                      int* __restrict__ scols, int E) {
    int e = blockIdx.x * 256 + threadIdx.x;
    if (e >= E) return;
    int r = rows[e];
    int pos = atomicAdd(&cursor[r], 1);
    svals[pos] = vals[e];
    scols[pos] = cols[e];
}

// ---------------- CSR SpMM bf16: y[row] = a*sum(val*x[col]) - beta*old[row]
// one wave per row; lane owns 8 bf16 (one uint4) of the 512-wide feature row.
// 4-deep edge unroll for memory-level parallelism.
__global__ __launch_bounds__(256) void spmm_bf16_kernel(const float* __restrict__ svals,
                                                        const int* __restrict__ scols,
                                                        const int* __restrict__ rowPtr,
                                                        const unsigned short* __restrict__ xsrc,
                                                        const unsigned short* __restrict__ xold,
                                                        unsigned short* __restrict__ y,
                                                        float alpha, int beta) {
    const int wid = threadIdx.x >> 6;
    const int lane = threadIdx.x & 63;
    const int row = blockIdx.x * 4 + wid;
    if (row >= V_NODES) return;
    const int s = rowPtr[row], e_end = rowPtr[row + 1];
    const uint4* __restrict__ xs = (const uint4*)xsrc;   // 64 uint4 per row

    float a0[8], a1[8];
    #pragma unroll
    for (int j = 0; j < 8; ++j) { a0[j] = 0.f; a1[j] = 0.f; }

    int e = s;
    for (; e + 3 < e_end; e += 4) {
        float w0 = svals[e],   w1 = svals[e+1], w2 = svals[e+2], w3 = svals[e+3];
        int   c0 = scols[e],   c1 = scols[e+1], c2 = scols[e+2], c3 = scols[e+3];
        uint4 q0 = xs[(size_t)c0 * 64 + lane];
        uint4 q1 = xs[(size_t)c1 * 64 + lane];
        uint4 q2 = xs[(size_t)c2 * 64 + lane];
        uint4 q3 = xs[(size_t)c3 * 64 + lane];
        unsigned int u0[4] = {q0.x, q0.y, q0.z, q0.w};
        unsigned int u1[4] = {q1.x, q1.y, q1.z, q1.w};
        unsigned int u2[4] = {q2.x, q2.y, q2.z, q2.w};
        unsigned int u3[4] = {q3.x, q3.y, q3.z, q3.w};
        #pragma unroll
        for (int j = 0; j < 4; ++j) {
            a0[2*j+0] += w0 * bf2f((unsigned short)(u0[j] & 0xffffu));
            a0[2*j+1] += w0 * bf2f((unsigned short)(u0[j] >> 16));
            a1[2*j+0] += w1 * bf2f((unsigned short)(u1[j] & 0xffffu));
            a1[2*j+1] += w1 * bf2f((unsigned short)(u1[j] >> 16));
            a0[2*j+0] += w2 * bf2f((unsigned short)(u2[j] & 0xffffu));
            a0[2*j+1] += w2 * bf2f((unsigned short)(u2[j] >> 16));
            a1[2*j+0] += w3 * bf2f((unsigned short)(u3[j] & 0xffffu));
            a1[2*j+1] += w3 * bf2f((unsigned short)(u3[j] >> 16));
        }
    }
    for (; e < e_end; ++e) {
        float w0 = svals[e];
        int c0 = scols[e];
        uint4 q0 = xs[(size_t)c0 * 64 + lane];
        unsigned int u0[4] = {q0.x, q0.y, q0.z, q0.w};
        #pragma unroll
        for (int j = 0; j < 4; ++j) {
            a0[2*j+0] += w0 * bf2f((unsigned short)(u0[j] & 0xffffu));
            a0[2*j+1] += w0 * bf2f((unsigned short)(u0[j] >> 16));
        }
    }

    float r[8];
    #pragma unroll
    for (int j = 0; j < 8; ++j) r[j] = alpha * (a0[j] + a1[j]);
    if (beta) {
        uint4 q = ((const uint4*)xold)[(size_t)row * 64 + lane];
        unsigned int u[4] = {q.x, q.y, q.z, q.w};
        #pragma unroll
        for (int j = 0; j < 4; ++j) {
            r[2*j+0] -= bf2f((unsigned short)(u[j] & 0xffffu));
            r[2*j+1] -= bf2f((unsigned short)(u[j] >> 16));
        }
    }
    uint4 o;
    unsigned int* ou = (unsigned int*)&o;
    #pragma unroll
    for (int j = 0; j < 4; ++j)
        ou[j] = (unsigned int)f2bf(r[2*j]) | ((unsigned int)f2bf(r[2*j+1]) << 16);
    ((uint4*)y)[(size_t)row * 64 + lane] = o;
}

// ---------------- fused MFMA GEMM over all K orders ------------------------
// out[b,co,v] = sum_{kci<640} T[kci>>7][v, b*128+(kci&127)] * WbT[co][kci] + bias[co]
// 128v x 128co tile, BK=64, double-buffered LDS A via global_load_lds (16B),
// XOR-swizzled (source-permute + read-permute, linear dest). B direct global.
__global__ __launch_bounds__(256) void gemm_mfma_kernel(const unsigned short* __restrict__ T,
                                                        const unsigned short* __restrict__ WbT,
                                                        const float* __restrict__ bias,
                                                        float* __restrict__ out) {
    __shared__ unsigned short Abuf[2][128 * 64];   // 2 x 16 KB
    const int lane = threadIdx.x & 63;
    const int wv = threadIdx.x >> 6;
    const int v0 = blockIdx.x * 128;
    const int b = blockIdx.y;
    const int lr = lane & 15;
    const int lk = lane >> 4;

    // --- staging address precompute (per lane, constant across steps) ---
    const int lanerow = lane >> 3;                 // 0..7 within 8-row slot
    const int cgp = (lane & 7) ^ lanerow;          // swizzled 16B col-group
    size_t goff[4];
    #pragma unroll
    for (int j = 0; j < 4; ++j) {
        int row_local = wv * 32 + j * 8 + lanerow;
        int rowg = v0 + row_local;
        if (rowg >= V_NODES) rowg = V_NODES - 1;   // clamp; rows masked at store
        goff[j] = (size_t)rowg * FDIM + b * CIN + cgp * 8;
    }

    f32x4 acc[8][2];
    #pragma unroll
    for (int mf = 0; mf < 8; ++mf)
        #pragma unroll
        for (int nf = 0; nf < 2; ++nf)
            acc[mf][nf] = (f32x4){0.f, 0.f, 0.f, 0.f};

    // prologue: stage step 0 into buf 0
    #pragma unroll
    for (int j = 0; j < 4; ++j)
        __builtin_amdgcn_global_load_lds(
            (const __attribute__((address_space(1))) void*)(T + goff[j]),
            (__attribute__((address_space(3))) void*)(&Abuf[0][(wv * 32 + j * 8) * 64]),
            16, 0, 0);
    __syncthreads();

    #pragma unroll 2
    for (int s = 0; s < 10; ++s) {     // 10 steps of BK=64 over KTOT=640
        const int cur = s & 1;
        if (s < 9) {
            const size_t stepoff = (size_t)((s + 1) >> 1) * V_NODES * FDIM + ((s + 1) & 1) * 64;
            #pragma unroll
            for (int j = 0; j < 4; ++j)
                __builtin_amdgcn_global_load_lds(
                    (const __attribute__((address_space(1))) void*)(T + goff[j] + stepoff),
                    (__attribute__((address_space(3))) void*)(&Abuf[cur ^ 1][(wv * 32 + j * 8) * 64]),
                    16, 0, 0);
        }
        const unsigned short* Ab = &Abuf[cur][0];
        #pragma unroll
        for (int c = 0; c < 2; ++c) {
            s16x8 bfr[2];
            #pragma unroll
            for (int nf = 0; nf < 2; ++nf)
                bfr[nf] = *(const s16x8*)(WbT + (size_t)(wv * 32 + nf * 16 + lr) * KTOT
                                          + s * 64 + c * 32 + lk * 8);
            s16x8 a[8];
            #pragma unroll
            for (int mf = 0; mf < 8; ++mf) {
                int rr = mf * 16 + lr;
                int slot = ((c * 4 + lk) ^ (lr & 7)) * 8;
                a[mf] = *(const s16x8*)(Ab + rr * 64 + slot);
            }
            #pragma unroll
            for (int mf = 0; mf < 8; ++mf)
                #pragma unroll
                for (int nf = 0; nf < 2; ++nf)
                    acc[mf][nf] = __builtin_amdgcn_mfma_f32_16x16x32_bf16(a[mf], bfr[nf], acc[mf][nf], 0, 0, 0);
        }
        __syncthreads();
    }

    // --- epilogue: transpose through LDS (reuse Abuf), coalesced stores ---
    float* lds_f = (float*)&Abuf[0][0];            // 32 co x 132 f32 = 16.9 KB
    const float bs0 = bias[wv * 32 + lr];
    const float bs1 = bias[wv * 32 + 16 + lr];
    #pragma unroll
    for (int p = 0; p < 4; ++p) {
        if (wv == p) {
            #pragma unroll
            for (int mf = 0; mf < 8; ++mf)
                #pragma unroll
                for (int nf = 0; nf < 2; ++nf) {
                    int co_l = nf * 16 + lr;               // 0..31
                    int vbase = mf * 16 + lk * 4;
                    f32x4 val = acc[mf][nf];
                    float bs = nf ? bs1 : bs0;
                    val[0] += bs; val[1] += bs; val[2] += bs; val[3] += bs;
                    *(f32x4*)(lds_f + co_l * 132 + vbase) = val;
                }
        }
        __syncthreads();
        #pragma unroll
        for (int i = 0; i < 4; ++i) {
            int flat = i * 256 + threadIdx.x;
            int co_l = flat >> 5;                          // 0..31
            int v4 = flat & 31;
            int v = v0 + v4 * 4;
            if (v < V_NODES) {
                f32x4 val = *(const f32x4*)(lds_f + co_l * 132 + v4 * 4);
                *(f32x4*)(out + (size_t)(b * COUT + p * 32 + co_l) * V_NODES + v) = val;
            }
        }
        __syncthreads();
    }
}

extern "C" void kernel_launch(void* const* d_in, const int* in_sizes, int n_in,
                              void* d_out, int out_size, void* d_ws, size_t ws_size,
                              hipStream_t stream) {
    const float* x    = (const float*)d_in[0];
    const float* vals = (const float*)d_in[1];
    const float* W    = (const float*)d_in[2];
    const float* bias = (const float*)d_in[3];
    const int* rows   = (const int*)d_in[4];
    const int* cols   = (const int*)d_in[5];
    const int E = in_sizes[1];
    float* out = (float*)d_out;

    // workspace: T0..T4 bf16 (each V*512), WbT bf16, CSR arrays
    unsigned short* T    = (unsigned short*)d_ws;
    unsigned short* WbT  = T + (size_t)KORD * V_NODES * FDIM;
    float* svals  = (float*)(WbT + (size_t)COUT * KTOT);
    int*   scols  = (int*)(svals + E);
    int*   rowPtr = scols + E;
    int*   cursor = rowPtr + V_NODES + 1;
    int*   cnt    = cursor + V_NODES;

    unsigned short* T0 = T;
    unsigned short* T1 = T + 1 * (size_t)V_NODES * FDIM;
    unsigned short* T2 = T + 2 * (size_t)V_NODES * FDIM;
    unsigned short* T3 = T + 3 * (size_t)V_NODES * FDIM;
    unsigned short* T4 = T + 4 * (size_t)V_NODES * FDIM;

    const int eBlocks = (E + 255) / 256;
    const int vBlocks = (V_NODES + 255) / 256;
    const int spBlocks = (V_NODES + 3) / 4;

    // CSR build
    zero_cnt_kernel<<<vBlocks, 256, 0, stream>>>(cnt);
    hist_kernel<<<eBlocks, 256, 0, stream>>>(rows, cnt, E);
    scan_kernel<<<1, 1024, 0, stream>>>(cnt, rowPtr, cursor);
    scatter_kernel<<<eBlocks, 256, 0, stream>>>(vals, rows, cols, cursor, svals, scols, E);

    // T0 + weights
    dim3 tg((V_NODES + 63) / 64, FDIM / 64);
    transpose_kernel<<<tg, 256, 0, stream>>>(x, T0);
    convw_kernel<<<(KTOT * COUT + 255) / 256, 256, 0, stream>>>(W, WbT);

    // Chebyshev recurrence (all bf16)
    spmm_bf16_kernel<<<spBlocks, 256, 0, stream>>>(svals, scols, rowPtr, T0, T0, T1, 1.f, 0);
    spmm_bf16_kernel<<<spBlocks, 256, 0, stream>>>(svals, scols, rowPtr, T1, T0, T2, 2.f, 1);
    spmm_bf16_kernel<<<spBlocks, 256, 0, stream>>>(svals, scols, rowPtr, T2, T1, T3, 2.f, 1);
    spmm_bf16_kernel<<<spBlocks, 256, 0, stream>>>(svals, scols, rowPtr, T3, T2, T4, 2.f, 1);

    // fused contraction over all 5 orders
    dim3 gg((V_NODES + 127) / 128, BATCH);
    gemm_mfma_kernel<<<gg, 256, 0, stream>>>(T, WbT, bias, out);
}